// Round 7
// baseline (173.278 us; speedup 1.0000x reference)
//
#include <hip/hip_runtime.h>

// Chamfer distance, exact, per-8-point-group outward walk over x-sorted clouds.
//
// R6 post-mortem: block-shared window is capped by the block's WORST point
// (y-z outliers force x-window ~ +/-0.7 -> ~50% of cloud scanned; VALUBusy fit
// confirms). Fix: groups of 8 points per wave, walking 64-target coalesced
// chunks outward with an exact per-group termination test. Sort parallelized
// (hist/scan/scatter, 64 blocks) replacing the 16us 8-block serial sort.
// 8192 wave-results -> partial array + reduce kernel (no same-address atomic
// storm). Exactness: remaining targets beyond chunk edge E (right) satisfy
// qx' >= E - BW (bucket-monotone) -> dist^2 >= clamp(E - BW - px)^2; stop
// when that exceeds the group-reduced running min for every point.

typedef float float4_t __attribute__((ext_vector_type(4)));

#define NB 1024
#define XLO_BND (-6.0f)
#define XSCALE (NB / 12.0f)
#define BWF (12.0f / NB)   // bucket width
#define PAD 128            // sentinel pad per side per cloud
#define GPTS 8             // points per wave in walk kernel

static __device__ __forceinline__ int bucket_of(float x) {
  float f = (x - XLO_BND) * XSCALE;
  f = fminf(fmaxf(f, 0.f), (float)(NB - 1));  // clamp BEFORE cast (fptosi UB)
  return (int)f;
}

// S1: per-cloud histogram via global atomics (8 clouds x M/1024 chunks)
__global__ __launch_bounds__(256) void hist_kernel(
    const float* __restrict__ pred, const float* __restrict__ target,
    int* __restrict__ ghist, int M) {
  int chunks = M / 1024;
  int c = blockIdx.x / chunks, chunk = blockIdx.x % chunks;
  const float* src = ((c & 1) ? target : pred) + (size_t)(c >> 1) * M * 3;
  int t = threadIdx.x;
#pragma unroll
  for (int u = 0; u < 4; ++u) {
    int i = chunk * 1024 + t + 256 * u;
    atomicAdd(&ghist[c * NB + bucket_of(src[3 * i])], 1);
  }
}

// S2: scan -> bstart; cursor in-place in ghist; write sentinel pads
__global__ __launch_bounds__(1024) void scan_kernel(
    int* __restrict__ ghist, int* __restrict__ bstart,
    float4_t* __restrict__ sorted, int M) {
  int c = blockIdx.x;
  __shared__ int sc[NB];
  int t = threadIdx.x;
  int h = ghist[c * NB + t];
  sc[t] = h;
  __syncthreads();
  for (int off = 1; off < NB; off <<= 1) {  // Hillis-Steele inclusive scan
    int v = sc[t];
    if (t >= off) v += sc[t - off];
    __syncthreads();
    sc[t] = v;
    __syncthreads();
  }
  int excl = sc[t] - h;
  bstart[c * (NB + 1) + t] = excl;
  if (t == 0) bstart[c * (NB + 1) + NB] = M;
  ghist[c * NB + t] = excl;  // becomes scatter cursor
  float4_t* base = sorted + (size_t)c * (M + 2 * PAD) + PAD;
  if (t < PAD) {
    // x sentinels force walk termination; huge-but-finite d2, no min effect
    base[-PAD + t] = (float4_t){-1.0e18f, 0.f, 0.f, 0.f};
    base[M + t] = (float4_t){1.0e18f, 0.f, 0.f, 0.f};
  }
}

// S3: scatter into padded sorted layout
__global__ __launch_bounds__(256) void scatter_kernel(
    const float* __restrict__ pred, const float* __restrict__ target,
    int* __restrict__ gcursor, float4_t* __restrict__ sorted, int M) {
  int chunks = M / 1024;
  int c = blockIdx.x / chunks, chunk = blockIdx.x % chunks;
  const float* src = ((c & 1) ? target : pred) + (size_t)(c >> 1) * M * 3;
  float4_t* base = sorted + (size_t)c * (M + 2 * PAD) + PAD;
  int t = threadIdx.x;
#pragma unroll
  for (int u = 0; u < 4; ++u) {
    int i = chunk * 1024 + t + 256 * u;
    float x = src[3 * i], y = src[3 * i + 1], z = src[3 * i + 2];
    int slot = atomicAdd(&gcursor[c * NB + bucket_of(x)], 1);
    base[slot] = (float4_t){x, y, z, x * x + y * y + z * z};
  }
}

// W: one wave per 8 points; bidirectional 64-target chunk walk, exact exit
__global__ __launch_bounds__(64) void walk_kernel(
    const float4_t* __restrict__ sorted, const int* __restrict__ bstart,
    float* __restrict__ partial, int M) {
  int wavesPerInst = M / GPTS;  // 1024
  int inst = blockIdx.x / wavesPerInst;
  int wi = blockIdx.x % wavesPerInst;
  int b = inst >> 1, dir = inst & 1;
  int cs = 2 * b + dir, cr = 2 * b + (dir ^ 1);
  int cstride = M + 2 * PAD;
  const float4_t* SP = sorted + (size_t)cs * cstride + PAD;
  const float4_t* RP = sorted + (size_t)cr * cstride + PAD;
  int lane = threadIdx.x;

  __shared__ float4_t pts8[GPTS];
  if (lane < GPTS) pts8[lane] = SP[wi * GPTS + lane];
  __syncthreads();
  float px[GPTS], py[GPTS], pz[GPTS], mn[GPTS];
#pragma unroll
  for (int k = 0; k < GPTS; ++k) {
    float4_t p = pts8[k];
    px[k] = p.x; py[k] = p.y; pz[k] = p.z;
    mn[k] = 1.0e30f;  // < sentinel gap^2 (1e36) so sentinels always terminate
  }
  int j0 = bstart[cr * (NB + 1) + bucket_of(px[0])];
  int jr = j0, jl = j0 - 64;
  bool doneR = false, doneL = false;  // wave-uniform
  float exR = -1.0e18f, exL = 1.0e18f;
  int it = 0;
  while (!(doneR && doneL)) {
    if (!doneR) {
      float4_t q = RP[jr + lane];  // coalesced 1KB/wave
      exR = __shfl(q.x, 63, 64);
#pragma unroll
      for (int k = 0; k < GPTS; ++k) {
        float dx = q.x - px[k], dy = q.y - py[k], dz = q.z - pz[k];
        float d2 = fmaf(dz, dz, fmaf(dy, dy, dx * dx));
        mn[k] = fminf(mn[k], d2);
      }
      jr += 64;
    }
    if (!doneL) {
      float4_t q = RP[jl + lane];
      exL = __shfl(q.x, 0, 64);
#pragma unroll
      for (int k = 0; k < GPTS; ++k) {
        float dx = q.x - px[k], dy = q.y - py[k], dz = q.z - pz[k];
        float d2 = fmaf(dz, dz, fmaf(dy, dy, dx * dx));
        mn[k] = fminf(mn[k], d2);
      }
      jl -= 64;
    }
    if ((++it & 1) == 0) {  // every 2 chunks: group-reduce mins, exit test
#pragma unroll
      for (int k = 0; k < GPTS; ++k)
#pragma unroll
        for (int off = 32; off > 0; off >>= 1)
          mn[k] = fminf(mn[k], __shfl_xor(mn[k], off, 64));
      bool allR = true, allL = true;
#pragma unroll
      for (int k = 0; k < GPTS; ++k) {
        float gr = fmaxf(exR - px[k] - BWF, 0.f);  // lower bound on remaining
        allR = allR && (gr * gr > mn[k]);
        float gl = fmaxf(px[k] - exL - BWF, 0.f);
        allL = allL && (gl * gl > mn[k]);
      }
      doneR = doneR || allR;
      doneL = doneL || allL;
    }
  }
  if (lane == 0) {  // mn[] is wave-reduced at exit (exit set only post-reduce)
    float s = 0.f;
#pragma unroll
    for (int k = 0; k < GPTS; ++k) s += mn[k];
    partial[blockIdx.x] = s;
  }
}

// R: sum partials -> out (writes out directly; out is poisoned each launch)
__global__ __launch_bounds__(256) void reduce_kernel(
    const float* __restrict__ partial, float* __restrict__ out, int n,
    float scale) {
  float s = 0.f;
  for (int i = threadIdx.x; i < n; i += 256) s += partial[i];
  for (int off = 32; off > 0; off >>= 1) s += __shfl_down(s, off, 64);
  __shared__ float ws[4];
  if ((threadIdx.x & 63) == 0) ws[threadIdx.x >> 6] = s;
  __syncthreads();
  if (threadIdx.x == 0) out[0] = (ws[0] + ws[1] + ws[2] + ws[3]) * scale;
}

extern "C" void kernel_launch(void* const* d_in, const int* in_sizes, int n_in,
                              void* d_out, int out_size, void* d_ws,
                              size_t ws_size, hipStream_t stream) {
  const float* pred = (const float*)d_in[0];
  const float* target = (const float*)d_in[1];
  float* out = (float*)d_out;
  const int B = 4;
  const int M = in_sizes[0] / (B * 3);  // 8192

  char* ws = (char*)d_ws;
  float4_t* sorted = (float4_t*)ws;                     // 8*(M+256)*16 B
  size_t off1 = (size_t)8 * (M + 2 * PAD) * 16;
  int* bstart = (int*)(ws + off1);                      // 8*(NB+1) ints
  size_t off2 = off1 + (size_t)8 * (NB + 1) * 4;
  int* ghist = (int*)(ws + off2);                       // 8*NB ints (hist->cursor)
  size_t off3 = off2 + (size_t)8 * NB * 4;
  float* partial = (float*)(ws + off3);                 // 8*M/GPTS floats

  float scale = 1.0f / (float)(B * M);  // sum_all/(B*M) == reference mean

  hipMemsetAsync(ghist, 0, (size_t)8 * NB * 4, stream);
  int chunks = 8 * (M / 1024);  // 64
  hist_kernel<<<chunks, 256, 0, stream>>>(pred, target, ghist, M);
  scan_kernel<<<8, 1024, 0, stream>>>(ghist, bstart, sorted, M);
  scatter_kernel<<<chunks, 256, 0, stream>>>(pred, target, ghist, sorted, M);
  int nwaves = 8 * (M / GPTS);  // 8192
  walk_kernel<<<nwaves, 64, 0, stream>>>(sorted, bstart, partial, M);
  reduce_kernel<<<1, 256, 0, stream>>>(partial, out, nwaves, scale);
}

// Round 8
// 146.187 us; speedup vs baseline: 1.1853x; 1.1853x over previous
//
#include <hip/hip_runtime.h>

// Chamfer distance, exact, per-8-point-group outward walk over x-sorted clouds.
//
// R7 post-mortem: walk was latency-bound (VALUBusy 33%, occ 19%): dependent
// load->compute->96-op butterfly->branch chain, no prefetch, 1-wave blocks.
// R8: (a) prefetch next chunk before computing current (clamped into sentinel
// pads so speculative loads are safe); (b) exit test = one scalar U=max_k mn
// vs gap from group's px extremes (conservative, exact: gmin^2>U => gap_k^2>
// mn_k for all k); (c) 256-thr blocks = 4 waves -> up to 32 waves/CU;
// (d) hist+scan fused (LDS hist, no memset) -> 4 dispatches total.
// Exactness: remaining targets right of computed chunk edge exR satisfy
// x >= exR - BW (bucket-monotone) -> d2 >= clamp(exR-BW-px)^2; stop side when
// that exceeds every point's current (wave-reduced) min. Sentinel pads
// (x=+/-1e18, d2~1e36 > mn_init=1e30) guarantee termination at both ends.

typedef float float4_t __attribute__((ext_vector_type(4)));

#define NB 1024
#define XLO_BND (-6.0f)
#define XSCALE (NB / 12.0f)
#define BWF (12.0f / NB)   // bucket width
#define PAD 128            // sentinel pad per side per cloud
#define GPTS 8             // points per wave in walk kernel
#define WPB 4              // waves per walk block

static __device__ __forceinline__ int bucket_of(float x) {
  float f = (x - XLO_BND) * XSCALE;
  f = fminf(fmaxf(f, 0.f), (float)(NB - 1));  // clamp BEFORE cast (fptosi UB)
  return (int)f;
}

// S1: per-cloud LDS histogram + scan + cursors + sentinel pads (8 blocks)
__global__ __launch_bounds__(1024) void hist_scan_kernel(
    const float* __restrict__ pred, const float* __restrict__ target,
    int* __restrict__ bstart, int* __restrict__ gcursor,
    float4_t* __restrict__ sorted, int M) {
  int c = blockIdx.x;  // cloud: 2*b + (0=pred,1=target)
  const float* src = ((c & 1) ? target : pred) + (size_t)(c >> 1) * M * 3;
  __shared__ int hist[NB], sc[NB];
  int t = threadIdx.x;
  hist[t] = 0;
  __syncthreads();
  for (int i = t; i < M; i += 1024) atomicAdd(&hist[bucket_of(src[3 * i])], 1);
  __syncthreads();
  sc[t] = hist[t];
  __syncthreads();
  for (int off = 1; off < NB; off <<= 1) {  // Hillis-Steele inclusive scan
    int v = sc[t];
    if (t >= off) v += sc[t - off];
    __syncthreads();
    sc[t] = v;
    __syncthreads();
  }
  int excl = sc[t] - hist[t];
  bstart[c * (NB + 1) + t] = excl;
  if (t == 0) bstart[c * (NB + 1) + NB] = M;
  gcursor[c * NB + t] = excl;
  float4_t* base = sorted + (size_t)c * (M + 2 * PAD) + PAD;
  if (t < PAD) {  // termination sentinels; d2 ~1e36 never wins a min
    base[-PAD + t] = (float4_t){-1.0e18f, 0.f, 0.f, 0.f};
    base[M + t] = (float4_t){1.0e18f, 0.f, 0.f, 0.f};
  }
}

// S2: scatter into padded sorted layout (64 blocks)
__global__ __launch_bounds__(256) void scatter_kernel(
    const float* __restrict__ pred, const float* __restrict__ target,
    int* __restrict__ gcursor, float4_t* __restrict__ sorted, int M) {
  int chunks = M / 1024;
  int c = blockIdx.x / chunks, chunk = blockIdx.x % chunks;
  const float* src = ((c & 1) ? target : pred) + (size_t)(c >> 1) * M * 3;
  float4_t* base = sorted + (size_t)c * (M + 2 * PAD) + PAD;
  int t = threadIdx.x;
#pragma unroll
  for (int u = 0; u < 4; ++u) {
    int i = chunk * 1024 + t + 256 * u;
    float x = src[3 * i], y = src[3 * i + 1], z = src[3 * i + 2];
    int slot = atomicAdd(&gcursor[c * NB + bucket_of(x)], 1);
    base[slot] = (float4_t){x, y, z, x * x + y * y + z * z};
  }
}

// W: one wave per 8 points; prefetched bidirectional chunk walk, exact exit
__global__ __launch_bounds__(256) void walk_kernel(
    const float4_t* __restrict__ sorted, const int* __restrict__ bstart,
    float* __restrict__ partial, int M) {
  int wavesPerInst = M / GPTS;  // 1024
  int gid = blockIdx.x * WPB + ((int)threadIdx.x >> 6);
  int inst = gid / wavesPerInst;
  int wi = gid % wavesPerInst;
  int b = inst >> 1, dir = inst & 1;
  int cs = 2 * b + dir, cr = 2 * b + (dir ^ 1);
  int cstride = M + 2 * PAD;
  const float4_t* SP = sorted + (size_t)cs * cstride + PAD;
  const float4_t* RP = sorted + (size_t)cr * cstride + PAD;
  int lane = threadIdx.x & 63;

  float px[GPTS], py[GPTS], pz[GPTS], mn[GPTS];
  float pxmn = 3.0e38f, pxmx = -3.0e38f;
#pragma unroll
  for (int k = 0; k < GPTS; ++k) {  // uniform-address loads (L1 broadcast)
    float4_t p = SP[wi * GPTS + k];
    px[k] = p.x; py[k] = p.y; pz[k] = p.z;
    mn[k] = 1.0e30f;  // < sentinel d2 (~1e36) so sentinels always terminate
    pxmn = fminf(pxmn, p.x);
    pxmx = fmaxf(pxmx, p.x);
  }
  int j0 = bstart[cr * (NB + 1) + bucket_of(0.5f * (pxmn + pxmx))];
  int jr = j0, jl = j0 - 64;
  const int jrmax = M + PAD - 64, jlmin = -PAD;  // clamp => loads always safe
  float4_t qr = RP[min(jr, jrmax) + lane];
  float4_t ql = RP[max(jl, jlmin) + lane];
  bool doneR = false, doneL = false;  // wave-uniform
  float exR = -3.0e38f, exL = 3.0e38f;
  int it = 0;
  while (true) {
    if (!doneR) {
      exR = __shfl(qr.x, 63, 64);  // edge of chunk being computed
      float4_t qn = RP[min(jr + 64, jrmax) + lane];  // prefetch next
#pragma unroll
      for (int k = 0; k < GPTS; ++k) {
        float dx = qr.x - px[k], dy = qr.y - py[k], dz = qr.z - pz[k];
        mn[k] = fminf(mn[k], fmaf(dz, dz, fmaf(dy, dy, dx * dx)));
      }
      jr += 64;
      qr = qn;
    }
    if (!doneL) {
      exL = __shfl(ql.x, 0, 64);
      float4_t qn = RP[max(jl - 64, jlmin) + lane];
#pragma unroll
      for (int k = 0; k < GPTS; ++k) {
        float dx = ql.x - px[k], dy = ql.y - py[k], dz = ql.z - pz[k];
        mn[k] = fminf(mn[k], fmaf(dz, dz, fmaf(dy, dy, dx * dx)));
      }
      jl -= 64;
      ql = qn;
    }
    if ((++it & 1) == 0) {  // every 2 chunk-rounds: reduce mins + exit test
#pragma unroll
      for (int k = 0; k < GPTS; ++k)
#pragma unroll
        for (int off = 32; off > 0; off >>= 1)
          mn[k] = fminf(mn[k], __shfl_xor(mn[k], off, 64));
      float U = 0.f;
#pragma unroll
      for (int k = 0; k < GPTS; ++k) U = fmaxf(U, mn[k]);
      float gR = fmaxf(exR - pxmx - BWF, 0.f);  // lower bound, remaining right
      float gL = fmaxf(pxmn - exL - BWF, 0.f);
      doneR = doneR || (gR * gR > U);
      doneL = doneL || (gL * gL > U);
      if (doneR && doneL) break;
    }
  }
  if (lane == 0) {  // mn[] fully reduced at every test point; exit only there
    float s = 0.f;
#pragma unroll
    for (int k = 0; k < GPTS; ++k) s += mn[k];
    partial[gid] = s;
  }
}

// R: sum partials -> out (direct write; out is re-poisoned each launch)
__global__ __launch_bounds__(256) void reduce_kernel(
    const float* __restrict__ partial, float* __restrict__ out, int n,
    float scale) {
  float s = 0.f;
  for (int i = threadIdx.x; i < n; i += 256) s += partial[i];
  for (int off = 32; off > 0; off >>= 1) s += __shfl_down(s, off, 64);
  __shared__ float ws[4];
  if ((threadIdx.x & 63) == 0) ws[threadIdx.x >> 6] = s;
  __syncthreads();
  if (threadIdx.x == 0) out[0] = (ws[0] + ws[1] + ws[2] + ws[3]) * scale;
}

extern "C" void kernel_launch(void* const* d_in, const int* in_sizes, int n_in,
                              void* d_out, int out_size, void* d_ws,
                              size_t ws_size, hipStream_t stream) {
  const float* pred = (const float*)d_in[0];
  const float* target = (const float*)d_in[1];
  float* out = (float*)d_out;
  const int B = 4;
  const int M = in_sizes[0] / (B * 3);  // 8192

  char* ws = (char*)d_ws;
  float4_t* sorted = (float4_t*)ws;                 // 8*(M+2*PAD)*16 B
  size_t off1 = (size_t)8 * (M + 2 * PAD) * 16;
  int* bstart = (int*)(ws + off1);                  // 8*(NB+1) ints
  size_t off2 = off1 + (size_t)8 * (NB + 1) * 4;
  int* gcursor = (int*)(ws + off2);                 // 8*NB ints
  size_t off3 = off2 + (size_t)8 * NB * 4;
  float* partial = (float*)(ws + off3);             // 8*M/GPTS floats

  float scale = 1.0f / (float)(B * M);  // sum_all/(B*M) == reference mean

  hist_scan_kernel<<<8, 1024, 0, stream>>>(pred, target, bstart, gcursor,
                                           sorted, M);
  int chunks = 8 * (M / 1024);  // 64
  scatter_kernel<<<chunks, 256, 0, stream>>>(pred, target, gcursor, sorted, M);
  int nwaves = 8 * (M / GPTS);  // 8192
  walk_kernel<<<nwaves / WPB, 256, 0, stream>>>(sorted, bstart, partial, M);
  reduce_kernel<<<1, 256, 0, stream>>>(partial, out, nwaves, scale);
}